// Round 2
// baseline (46.662 us; speedup 1.0000x reference)
//
#include <hip/hip_runtime.h>
#include <math.h>

#define ALPHA 0.2f

constexpr int BB   = 2;
constexpr int NN   = 512;
constexpr int FIN  = 256;
constexpr int FOUT = 128;

// ---------------------------------------------------------------------------
// Kernel A: Wh[b,n,o] = sum_f x[b,n,f] * W[f,o]
// grid 256 blocks (4 rows each), 128 threads.
// thread: row_local = t>>5 (0..3), o0 = (t&31)*4 -> float4 accumulator
// ---------------------------------------------------------------------------
__global__ __launch_bounds__(128) void wh_kernel(const float* __restrict__ x,
                                                 const float* __restrict__ W,
                                                 float* __restrict__ Wh) {
    __shared__ float xs[4][FIN];
    const int t = threadIdx.x;
    const int row0 = blockIdx.x * 4;

    // stage 4 rows of x (4*256 floats = 256 float4) coalesced
    const float4* xg = (const float4*)(x + (size_t)row0 * FIN);
    float4* xsv = (float4*)&xs[0][0];
    xsv[t]       = xg[t];
    xsv[t + 128] = xg[t + 128];
    __syncthreads();

    const int rl = t >> 5;         // 0..3
    const int o0 = (t & 31) * 4;   // 0..124
    float4 acc = {0.f, 0.f, 0.f, 0.f};
#pragma unroll 4
    for (int f = 0; f < FIN; ++f) {
        const float  xv = xs[rl][f];
        const float4 wv = *(const float4*)(W + (size_t)f * FOUT + o0);
        acc.x = fmaf(xv, wv.x, acc.x);
        acc.y = fmaf(xv, wv.y, acc.y);
        acc.z = fmaf(xv, wv.z, acc.z);
        acc.w = fmaf(xv, wv.w, acc.w);
    }
    *(float4*)(Wh + (size_t)(row0 + rl) * FOUT + o0) = acc;
}

// ---------------------------------------------------------------------------
// Kernel B: e[b,i,j] = sum_o a[o] * lrelu(Wh[b,i,o] + Wh[b,j,o])
// grid (16 j-tiles, 16 i-tiles, 2 batches), 128 threads, 32x32 tile.
// thread owns 2 i's (gi, gi+16) x 4 j's (gj+8m) -> strided so all LDS b128
// reads land on 8 distinct bank-quads (conflict-free).
// Also emits per-block partial sum of e^2 (deterministic tree, no atomics).
// ---------------------------------------------------------------------------
__global__ __launch_bounds__(128) void e_kernel(const float* __restrict__ Wh,
                                                const float* __restrict__ a_fc,
                                                float* __restrict__ e_buf,
                                                float* __restrict__ partials) {
    __shared__ float whi[32][132];   // pad 132: 16B-aligned rows
    __shared__ float whj[32][132];
    __shared__ float a_s[FOUT];
    __shared__ float red[2];

    const int t   = threadIdx.x;
    const int bj0 = blockIdx.x * 32;
    const int bi0 = blockIdx.y * 32;
    const int b   = blockIdx.z;
    const float* whb = Wh + (size_t)b * NN * FOUT;

    a_s[t] = a_fc[t];  // FOUT == blockDim.x == 128

    // stage both 32x128 tiles, float4-coalesced
#pragma unroll
    for (int it = 0; it < 8; ++it) {
        const int idx = it * 128 + t;       // float4 index 0..1023
        const int row = idx >> 5;           // 0..31
        const int c4  = idx & 31;           // 0..31
        const float4 vi = *(const float4*)(whb + (size_t)(bi0 + row) * FOUT + c4 * 4);
        const float4 vj = *(const float4*)(whb + (size_t)(bj0 + row) * FOUT + c4 * 4);
        *(float4*)&whi[row][c4 * 4] = vi;
        *(float4*)&whj[row][c4 * 4] = vj;
    }
    __syncthreads();

    const int gi = t >> 3;  // 0..15
    const int gj = t & 7;   // 0..7

    float acc[2][4] = {{0.f,0.f,0.f,0.f},{0.f,0.f,0.f,0.f}};

    for (int c = 0; c < 32; ++c) {
        const float4 av  = *(const float4*)&a_s[c * 4];
        float4 wi[2], wj[4];
        wi[0] = *(const float4*)&whi[gi][c * 4];
        wi[1] = *(const float4*)&whi[gi + 16][c * 4];
#pragma unroll
        for (int m = 0; m < 4; ++m)
            wj[m] = *(const float4*)&whj[gj + 8 * m][c * 4];

#pragma unroll
        for (int r = 0; r < 2; ++r) {
#pragma unroll
            for (int m = 0; m < 4; ++m) {
                float s;
                s = wi[r].x + wj[m].x; acc[r][m] = fmaf(av.x, fmaxf(s, ALPHA * s), acc[r][m]);
                s = wi[r].y + wj[m].y; acc[r][m] = fmaf(av.y, fmaxf(s, ALPHA * s), acc[r][m]);
                s = wi[r].z + wj[m].z; acc[r][m] = fmaf(av.z, fmaxf(s, ALPHA * s), acc[r][m]);
                s = wi[r].w + wj[m].w; acc[r][m] = fmaf(av.w, fmaxf(s, ALPHA * s), acc[r][m]);
            }
        }
    }

    // store e + local sum of squares
    float ss = 0.f;
#pragma unroll
    for (int r = 0; r < 2; ++r) {
#pragma unroll
        for (int m = 0; m < 4; ++m) {
            const float ev = acc[r][m];
            ss = fmaf(ev, ev, ss);
            const int gi_g = bi0 + gi + 16 * r;
            const int gj_g = bj0 + gj + 8 * m;
            e_buf[((size_t)(b * NN + gi_g)) * NN + gj_g] = ev;
        }
    }

#pragma unroll
    for (int off = 32; off; off >>= 1) ss += __shfl_down(ss, off);
    if ((t & 63) == 0) red[t >> 6] = ss;
    __syncthreads();
    if (t == 0)
        partials[blockIdx.z * 256 + blockIdx.y * 16 + blockIdx.x] = red[0] + red[1];
}

// ---------------------------------------------------------------------------
// Kernel D: norm -> mask -> softmax(row) -> h' = att @ Wh -> elu
// grid 256 blocks (4 rows each), 256 threads.
// Each block re-reduces the 512 partials itself (deterministic, saves launch).
// ---------------------------------------------------------------------------
__global__ __launch_bounds__(256) void softmax_pv_kernel(
        const float* __restrict__ e_buf, const int* __restrict__ adj,
        const float* __restrict__ Wh, const float* __restrict__ partials,
        float* __restrict__ out) {
    __shared__ float p[4][NN];
    __shared__ float hbuf[4][FOUT];
    __shared__ float smax[4][4];
    __shared__ float ssum[4][4];
    __shared__ float snorm[4];

    const int t = threadIdx.x;
    const int w = t >> 6;

    // --- global Frobenius norm from the 512 block partials ---
    float v = partials[t] + partials[t + 256];
#pragma unroll
    for (int off = 32; off; off >>= 1) v += __shfl_down(v, off);
    if ((t & 63) == 0) snorm[w] = v;
    __syncthreads();
    const float total    = snorm[0] + snorm[1] + snorm[2] + snorm[3];
    const float inv_norm = 1.0f / sqrtf(total);

    const int g0 = blockIdx.x * 4;
    float rs[4];

#pragma unroll
    for (int r = 0; r < 4; ++r) {
        const int g = g0 + r;
        const float* erow = e_buf + (size_t)g * NN;
        const int*   arow = adj   + (size_t)g * NN;

        float e0 = arow[t]       ? erow[t]       * inv_norm : -INFINITY;
        float e1 = arow[t + 256] ? erow[t + 256] * inv_norm : -INFINITY;

        float mx = fmaxf(e0, e1);
#pragma unroll
        for (int off = 32; off; off >>= 1) mx = fmaxf(mx, __shfl_down(mx, off));
        if ((t & 63) == 0) smax[r][w] = mx;
        __syncthreads();
        mx = fmaxf(fmaxf(smax[r][0], smax[r][1]), fmaxf(smax[r][2], smax[r][3]));

        const float p0 = expf(e0 - mx);
        const float p1 = expf(e1 - mx);
        p[r][t]       = p0;
        p[r][t + 256] = p1;

        float sm = p0 + p1;
#pragma unroll
        for (int off = 32; off; off >>= 1) sm += __shfl_down(sm, off);
        __syncthreads();                 // smax reads done before ssum reuse barrier
        if ((t & 63) == 0) ssum[r][w] = sm;
        __syncthreads();
        rs[r] = 1.0f / (ssum[r][0] + ssum[r][1] + ssum[r][2] + ssum[r][3]);
    }
    __syncthreads();  // all p[] visible

    // --- PV: h'[r][o] = (sum_j p[r][j] * Wh[b][j][o]) * rs[r], then elu ---
    const int o = t & 127;
    const int h = t >> 7;
    const int b = g0 >> 9;               // 4-row blocks never straddle batches
    const float* whb = Wh + (size_t)b * NN * FOUT;

    float acc[4] = {0.f, 0.f, 0.f, 0.f};
    const int j0 = h * 256;
#pragma unroll 4
    for (int j = j0; j < j0 + 256; ++j) {
        const float wv = whb[(size_t)j * FOUT + o];
#pragma unroll
        for (int r = 0; r < 4; ++r) acc[r] = fmaf(p[r][j], wv, acc[r]);
    }

    if (h) {
#pragma unroll
        for (int r = 0; r < 4; ++r) hbuf[r][o] = acc[r];
    }
    __syncthreads();
    if (!h) {
#pragma unroll
        for (int r = 0; r < 4; ++r) {
            const float hv = (acc[r] + hbuf[r][o]) * rs[r];
            out[(size_t)(g0 + r) * FOUT + o] = (hv > 0.f) ? hv : expm1f(hv);
        }
    }
}

// ---------------------------------------------------------------------------
extern "C" void kernel_launch(void* const* d_in, const int* in_sizes, int n_in,
                              void* d_out, int out_size, void* d_ws, size_t ws_size,
                              hipStream_t stream) {
    const float* x    = (const float*)d_in[0];
    const int*   adj  = (const int*)d_in[1];
    const float* W    = (const float*)d_in[2];
    const float* a_fc = (const float*)d_in[3];
    float* out = (float*)d_out;

    float* ws       = (float*)d_ws;
    float* Wh       = ws;                       // 2*512*128   = 131072 floats
    float* e_buf    = ws + 131072;              // 2*512*512   = 524288 floats
    float* partials = ws + 131072 + 524288;     // 512 floats

    // A: Wh = x @ W
    wh_kernel<<<dim3(BB * NN / 4), dim3(128), 0, stream>>>(x, W, Wh);

    // B: e + per-block sum(e^2) partials
    e_kernel<<<dim3(NN / 32, NN / 32, BB), dim3(128), 0, stream>>>(Wh, a_fc, e_buf, partials);

    // D: norm -> mask -> softmax -> PV -> elu
    softmax_pv_kernel<<<dim3(BB * NN / 4), dim3(256), 0, stream>>>(e_buf, adj, Wh, partials, out);
}